// Round 6
// baseline (281.299 us; speedup 1.0000x reference)
//
#include <hip/hip_runtime.h>
#include <hip/hip_bf16.h>

// GAT layer: B=8, N=2048, Fin=Fout=256
// h (f32), adj (i32 0/1), W (f32 256x256), a (f32 512x1) -> out f32 (8,2048,256)

typedef __bf16 bf16x8 __attribute__((ext_vector_type(8)));
typedef float f32x4 __attribute__((ext_vector_type(4)));
typedef unsigned short u16x8 __attribute__((ext_vector_type(8)));

__device__ __forceinline__ unsigned short f2bf(float f) {
    unsigned int u = __float_as_uint(f);
    u += 0x7FFFu + ((u >> 16) & 1u);   // round-to-nearest-even
    return (unsigned short)(u >> 16);
}

__device__ __forceinline__ void gld_lds16(const void* g, void* l) {
    __builtin_amdgcn_global_load_lds(
        (const __attribute__((address_space(1))) unsigned int*)g,
        (__attribute__((address_space(3))) unsigned int*)l, 16, 0, 0);
}

// ---------------- K-1: adj (i32) -> bitmask, permuted layout ---------------
// byte at row r, idx j covers n in [8j,8j+8); stored at r*256 + (j&7)*32 + (j>>3)
// so k_attn thread (tm,ts) reads byte ts*32 + nt per tile nt.
__global__ void k_mask(const int* __restrict__ adj, unsigned char* __restrict__ mask) {
    __shared__ unsigned char lb[256];
    int r = blockIdx.x;            // 16384 rows
    int t = threadIdx.x;           // byte j = t
    const int* ap = adj + (size_t)r * 2048 + t * 8;
    int4 A0 = *(const int4*)ap;
    int4 A1 = *(const int4*)(ap + 4);
    unsigned byt = (A0.x > 0) | ((A0.y > 0) << 1) | ((A0.z > 0) << 2) | ((A0.w > 0) << 3)
                 | ((A1.x > 0) << 4) | ((A1.y > 0) << 5) | ((A1.z > 0) << 6) | ((A1.w > 0) << 7);
    lb[(t & 7) * 32 + (t >> 3)] = (unsigned char)byt;
    __syncthreads();
    mask[(size_t)r * 256 + t] = lb[t];
}

// ---------------- K0: WT = W^T (bf16), wa1/wa2 = W@a1, W@a2 (f32) ----------
__global__ void k_prep(const float* __restrict__ W, const float* __restrict__ a,
                       unsigned short* __restrict__ WT,
                       float* __restrict__ wa1, float* __restrict__ wa2) {
    int t = threadIdx.x;
    int bid = blockIdx.x;
    if (bid < 256) {
        int o = bid;
        WT[o * 256 + t] = f2bf(W[t * 256 + o]);
    } else {
        float acc1 = 0.f, acc2 = 0.f;
        for (int o = 0; o < 256; o++) {
            float w = W[t * 256 + o];
            acc1 += w * a[o];
            acc2 += w * a[256 + o];
        }
        wa1[t] = acc1; wa2[t] = acc2;
    }
}

// ---------------- K1: s1[r]=h[r]·wa1, s2[r]=h[r]·wa2  (full f32) -----------
// 512 blocks, 8 lanes per row, shfl-xor reduce.
__global__ void k_scores(const float* __restrict__ h, const float* __restrict__ wa1,
                         const float* __restrict__ wa2,
                         float* __restrict__ s1, float* __restrict__ s2) {
    __shared__ float w1[256], w2[256];
    int t = threadIdx.x;
    w1[t] = wa1[t]; w2[t] = wa2[t];
    __syncthreads();
    int row = blockIdx.x * 32 + (t >> 3);
    int seg = t & 7;
    const float* hr = h + (size_t)row * 256 + seg * 32;
    const float* wp1 = w1 + seg * 32;
    const float* wp2 = w2 + seg * 32;
    float acc1 = 0.f, acc2 = 0.f;
#pragma unroll
    for (int i = 0; i < 32; i += 4) {
        float4 v = *(const float4*)(hr + i);
        acc1 += v.x * wp1[i] + v.y * wp1[i + 1] + v.z * wp1[i + 2] + v.w * wp1[i + 3];
        acc2 += v.x * wp2[i] + v.y * wp2[i + 1] + v.z * wp2[i + 2] + v.w * wp2[i + 3];
    }
#pragma unroll
    for (int d = 1; d < 8; d <<= 1) {
        acc1 += __shfl_xor(acc1, d, 64);
        acc2 += __shfl_xor(acc2, d, 64);
    }
    if (seg == 0) { s1[row] = acc1; s2[row] = acc2; }
}

// ---------------- K2: whT[o][r] = bf16( (h@W)[r][o] ) ----------------------
__global__ __launch_bounds__(256, 2)
void k_whT(const float* __restrict__ h, const unsigned short* __restrict__ WT,
           unsigned short* __restrict__ whT) {
    __shared__ __align__(16) unsigned char smem[65536];
    int tid = threadIdx.x, w = tid >> 6, l = tid & 63;
    int bid = blockIdx.x, ot = bid & 3, rt = bid >> 2;
    unsigned short* h_lds = (unsigned short*)(smem + 32768);

    {
        const unsigned char* WTb = (const unsigned char*)WT + (size_t)ot * 32768;
#pragma unroll
        for (int j = 0; j < 8; j++) {
            int chunk = w * 8 + j;
            int o = chunk * 2 + (l >> 5);
            int kb = (l & 31) * 16;
            gld_lds16(WTb + o * 512 + (kb ^ ((o & 7) << 4)), smem + chunk * 1024);
        }
    }
    {
        int rl = tid >> 2, cs = tid & 3;
        const float* hp = h + ((size_t)(rt * 64 + rl)) * 256 + cs * 64;
        int swz = (rl & 7) << 4;
        unsigned char* dst = (unsigned char*)(h_lds + rl * 256);
#pragma unroll
        for (int q = 0; q < 8; q++) {
            float4 v0 = *(const float4*)(hp + q * 8);
            float4 v1 = *(const float4*)(hp + q * 8 + 4);
            u16x8 pk;
            pk[0] = f2bf(v0.x); pk[1] = f2bf(v0.y); pk[2] = f2bf(v0.z); pk[3] = f2bf(v0.w);
            pk[4] = f2bf(v1.x); pk[5] = f2bf(v1.y); pk[6] = f2bf(v1.z); pk[7] = f2bf(v1.w);
            *(u16x8*)(dst + ((cs * 128 + q * 16) ^ swz)) = pk;
        }
    }
    __syncthreads();

    int l15 = l & 15, g = l >> 4;
    int oh = (w & 1) * 32, rh = (w >> 1) * 32;
    int swzr = (l15 & 7) << 4;
    f32x4 acc[2][2] = {};
#pragma unroll
    for (int kc = 0; kc < 8; kc++) {
        int kbyte = kc * 64 + 16 * g;
        bf16x8 A[2], Bv[2];
#pragma unroll
        for (int oi = 0; oi < 2; oi++)
            A[oi] = *(const bf16x8*)(smem + (oh + oi * 16 + l15) * 512 + (kbyte ^ swzr));
#pragma unroll
        for (int rj = 0; rj < 2; rj++)
            Bv[rj] = *(const bf16x8*)((unsigned char*)h_lds + (rh + rj * 16 + l15) * 512 + (kbyte ^ swzr));
#pragma unroll
        for (int oi = 0; oi < 2; oi++)
#pragma unroll
            for (int rj = 0; rj < 2; rj++)
                acc[oi][rj] = __builtin_amdgcn_mfma_f32_16x16x32_bf16(A[oi], Bv[rj], acc[oi][rj], 0, 0, 0);
    }
    __syncthreads();
    unsigned short* LT = h_lds;
#pragma unroll
    for (int oi = 0; oi < 2; oi++)
#pragma unroll
        for (int rj = 0; rj < 2; rj++)
#pragma unroll
            for (int jj = 0; jj < 4; jj++) {
                int o = oh + oi * 16 + g * 4 + jj;
                int r = rh + rj * 16 + l15;
                LT[o * 72 + r] = f2bf(acc[oi][rj][jj]);
            }
    __syncthreads();
    {
        int o = tid >> 2, seg = tid & 3;
        u16x8 v0 = *(const u16x8*)(LT + o * 72 + seg * 16);
        u16x8 v1 = *(const u16x8*)(LT + o * 72 + seg * 16 + 8);
        unsigned short* dst = whT + (size_t)(ot * 64 + o) * 16384 + rt * 64 + seg * 16;
        *(u16x8*)dst = v0;
        *(u16x8*)(dst + 8) = v1;
    }
}

// ---------------- K3: fused mask/exp/softmax/PV, double-buffered -----------
// LDS: buf0 [0,32K) buf1 [32K,64K) whT tiles [256o][64n] bf16 (src-swizzled);
//      P [65536,70144) 32x144B; S2 [70144,78336); S1 [78336,78464); RS [78464,78592)
__global__ __launch_bounds__(256, 2)
void k_attn(const unsigned char* __restrict__ mask, const unsigned short* __restrict__ whT,
            const float* __restrict__ s1, const float* __restrict__ s2,
            float* __restrict__ out) {
    __shared__ __align__(16) unsigned char smem[78592];
    int tid = threadIdx.x, w = tid >> 6, l = tid & 63;
    int b = blockIdx.x & 7, mt = blockIdx.x >> 3;   // batch pinned per-XCD for whT L2 residency
    int m0 = mt * 32;
    unsigned short* P = (unsigned short*)(smem + 65536);
    float* S2 = (float*)(smem + 70144);
    float* S1 = (float*)(smem + 78336);
    float* RS = (float*)(smem + 78464);

    if (tid < 32) S1[tid] = s1[b * 2048 + m0 + tid];
    {
        const float* sp = s2 + b * 2048 + tid * 8;
        *(f32x4*)(S2 + tid * 8) = *(const f32x4*)sp;
        *(f32x4*)(S2 + tid * 8 + 4) = *(const f32x4*)(sp + 4);
    }
    const unsigned char* src0 = (const unsigned char*)whT + (size_t)(b * 2048) * 2;

    // prologue: stage tile 0 -> buf0
#pragma unroll
    for (int j = 0; j < 8; j++) {
        int chunk = w * 8 + j;
        int o = chunk * 8 + (l >> 3);
        int kb = (l & 7) * 16;
        gld_lds16(src0 + (size_t)o * 32768 + (kb ^ ((o & 7) << 4)), smem + chunk * 1024);
    }
    asm volatile("s_waitcnt lgkmcnt(0)" ::: "memory");
    __builtin_amdgcn_s_barrier();
    __builtin_amdgcn_sched_barrier(0);

    f32x4 acc[4][2] = {};
    f32x4 rs[2] = {};
    u16x8 onesu;
#pragma unroll
    for (int i = 0; i < 8; i++) onesu[i] = 0x3F80;
    bf16x8 ones = *(bf16x8*)&onesu;

    int tm = tid >> 3, ts = tid & 7;
    float s1v = S1[tm];
    const unsigned char* maskRow = mask + ((size_t)(b * 2048 + m0 + tm)) * 256 + ts * 32;
    int l15 = l & 15, g = l >> 4;
    int swz = (l15 & 7) << 4;
    int cur = 0;

    for (int nt = 0; nt < 32; nt++) {
        // mask byte first (in-order vmcnt: its wait implies last tile's stage landed)
        unsigned char mb = maskRow[nt];
        // issue next tile's stage
        if (nt < 31) {
            int n0b = (nt + 1) * 128;
            unsigned bufoff = (unsigned)(cur ^ 1) * 32768u;
#pragma unroll
            for (int j = 0; j < 8; j++) {
                int chunk = w * 8 + j;
                int o = chunk * 8 + (l >> 3);
                int kb = (l & 7) * 16;
                gld_lds16(src0 + (size_t)o * 32768 + n0b + (kb ^ ((o & 7) << 4)),
                          smem + bufoff + chunk * 1024);
            }
        }
        // P[m][n'] = adj ? exp(LeakyReLU(s1+s2)) : 0   (bf16)
        {
            const float* s2p = S2 + nt * 64 + ts * 8;
            f32x4 sv0 = *(const f32x4*)s2p;
            f32x4 sv1 = *(const f32x4*)(s2p + 4);
            u16x8 pk;
#pragma unroll
            for (int e = 0; e < 4; e++) {
                float x = s1v + sv0[e];
                x = x > 0.f ? x : 0.2f * x;
                float p = (mb >> e) & 1 ? __expf(x) : 0.f;
                pk[e] = f2bf(p);
            }
#pragma unroll
            for (int e = 0; e < 4; e++) {
                float x = s1v + sv1[e];
                x = x > 0.f ? x : 0.2f * x;
                float p = (mb >> (e + 4)) & 1 ? __expf(x) : 0.f;
                pk[e + 4] = f2bf(p);
            }
            *(u16x8*)((unsigned char*)P + tm * 144 + ts * 16) = pk;
        }
        asm volatile("s_waitcnt lgkmcnt(0)" ::: "memory");
        __builtin_amdgcn_s_barrier();
        __builtin_amdgcn_sched_barrier(0);

        const unsigned char* bufb = smem + (unsigned)cur * 32768u;
        __builtin_amdgcn_s_setprio(1);
#pragma unroll
        for (int kc = 0; kc < 2; kc++) {
            int kbyte = kc * 64 + 16 * g;
            bf16x8 Bv[2];
#pragma unroll
            for (int mj = 0; mj < 2; mj++)
                Bv[mj] = *(const bf16x8*)((const unsigned char*)P + (mj * 16 + l15) * 144 + kbyte);
#pragma unroll
            for (int oi = 0; oi < 4; oi++) {
                bf16x8 Av = *(const bf16x8*)(bufb + (w * 64 + oi * 16 + l15) * 128 + (kbyte ^ swz));
#pragma unroll
                for (int mj = 0; mj < 2; mj++)
                    acc[oi][mj] = __builtin_amdgcn_mfma_f32_16x16x32_bf16(Av, Bv[mj], acc[oi][mj], 0, 0, 0);
            }
            if (w == 0) {
#pragma unroll
                for (int mj = 0; mj < 2; mj++)
                    rs[mj] = __builtin_amdgcn_mfma_f32_16x16x32_bf16(ones, Bv[mj], rs[mj], 0, 0, 0);
            }
        }
        __builtin_amdgcn_s_setprio(0);
        __builtin_amdgcn_sched_barrier(0);
        __builtin_amdgcn_s_barrier();
        __builtin_amdgcn_sched_barrier(0);
        cur ^= 1;
    }

    if (w == 0 && l < 16) { RS[l] = rs[0][0]; RS[16 + l] = rs[1][0]; }
    __syncthreads();
    float inv[2];
#pragma unroll
    for (int mj = 0; mj < 2; mj++) {
        float r_ = RS[mj * 16 + l15];
        inv[mj] = r_ > 0.f ? 1.0f / r_ : 0.f;
    }
    float* EP = (float*)(smem + w * 8704);
#pragma unroll
    for (int oi = 0; oi < 4; oi++)
#pragma unroll
        for (int mj = 0; mj < 2; mj++)
#pragma unroll
            for (int jj = 0; jj < 4; jj++)
                EP[(mj * 16 + l15) * 68 + oi * 16 + g * 4 + jj] = acc[oi][mj][jj] * inv[mj];
    __syncthreads();
    {
        int lm = l >> 3, os = l & 7;
#pragma unroll
        for (int mq = 0; mq < 4; mq++) {
            int m = mq * 8 + lm;
            f32x4 v0 = *(const f32x4*)(EP + m * 68 + os * 8);
            f32x4 v1 = *(const f32x4*)(EP + m * 68 + os * 8 + 4);
            float* dst = out + ((size_t)b * 2048 + m0 + m) * 256 + w * 64 + os * 8;
            *(f32x4*)dst = v0;
            *(f32x4*)(dst + 4) = v1;
        }
    }
}

extern "C" void kernel_launch(void* const* d_in, const int* in_sizes, int n_in,
                              void* d_out, int out_size, void* d_ws, size_t ws_size,
                              hipStream_t stream) {
    const float* h = (const float*)d_in[0];
    const int* adj = (const int*)d_in[1];
    const float* W = (const float*)d_in[2];
    const float* a = (const float*)d_in[3];
    float* out = (float*)d_out;

    unsigned char* ws = (unsigned char*)d_ws;
    unsigned short* whT = (unsigned short*)ws;                // 8,388,608
    unsigned short* WT  = (unsigned short*)(ws + 8388608);    //   131,072
    float* wa1 = (float*)(ws + 8519680);                      //     1,024
    float* wa2 = (float*)(ws + 8520704);                      //     1,024
    float* s1  = (float*)(ws + 8521728);                      //    65,536
    float* s2  = (float*)(ws + 8587264);                      //    65,536
    unsigned char* mask = ws + 8652800;                       // 4,194,304  (total ~12.25 MB)

    k_mask  <<<16384, 256, 0, stream>>>(adj, mask);
    k_prep  <<<257,   256, 0, stream>>>(W, a, WT, wa1, wa2);
    k_scores<<<512,   256, 0, stream>>>(h, wa1, wa2, s1, s2);
    k_whT   <<<1024,  256, 0, stream>>>(h, WT, whT);
    k_attn  <<<512,   256, 0, stream>>>(mask, whT, s1, s2, out);
}

// Round 9
// 244.476 us; speedup vs baseline: 1.1506x; 1.1506x over previous
//
#include <hip/hip_runtime.h>
#include <hip/hip_bf16.h>

// GAT layer: B=8, N=2048, Fin=Fout=256
// h (f32), adj (i32 0/1), W (f32 256x256), a (f32 512x1) -> out f32 (8,2048,256)

typedef __bf16 bf16x8 __attribute__((ext_vector_type(8)));
typedef float f32x4 __attribute__((ext_vector_type(4)));
typedef unsigned short u16x8 __attribute__((ext_vector_type(8)));

__device__ __forceinline__ unsigned short f2bf(float f) {
    unsigned int u = __float_as_uint(f);
    u += 0x7FFFu + ((u >> 16) & 1u);   // round-to-nearest-even
    return (unsigned short)(u >> 16);
}

__device__ __forceinline__ void gld_lds16(const void* g, void* l) {
    __builtin_amdgcn_global_load_lds(
        (const __attribute__((address_space(1))) unsigned int*)g,
        (__attribute__((address_space(3))) unsigned int*)l, 16, 0, 0);
}

// ---------------- K0: WT = W^T (bf16), wa1/wa2 = W@a1, W@a2 (f32) ----------
__global__ void k_prep(const float* __restrict__ W, const float* __restrict__ a,
                       unsigned short* __restrict__ WT,
                       float* __restrict__ wa1, float* __restrict__ wa2) {
    int t = threadIdx.x;
    int bid = blockIdx.x;
    if (bid < 256) {
        int o = bid;
        WT[o * 256 + t] = f2bf(W[t * 256 + o]);
    } else {
        float acc1 = 0.f, acc2 = 0.f;
        for (int o = 0; o < 256; o++) {
            float w = W[t * 256 + o];
            acc1 += w * a[o];
            acc2 += w * a[256 + o];
        }
        wa1[t] = acc1; wa2[t] = acc2;
    }
}

// ---------------- K1: s1[r]=h[r]·wa1, s2[r]=h[r]·wa2  (full f32) -----------
__global__ void k_scores(const float* __restrict__ h, const float* __restrict__ wa1,
                         const float* __restrict__ wa2,
                         float* __restrict__ s1, float* __restrict__ s2) {
    __shared__ float w1[256], w2[256];
    int t = threadIdx.x;
    w1[t] = wa1[t]; w2[t] = wa2[t];
    __syncthreads();
    int row = blockIdx.x * 32 + (t >> 3);
    int seg = t & 7;
    const float* hr = h + (size_t)row * 256 + seg * 32;
    const float* wp1 = w1 + seg * 32;
    const float* wp2 = w2 + seg * 32;
    float acc1 = 0.f, acc2 = 0.f;
#pragma unroll
    for (int i = 0; i < 32; i += 4) {
        float4 v = *(const float4*)(hr + i);
        acc1 += v.x * wp1[i] + v.y * wp1[i + 1] + v.z * wp1[i + 2] + v.w * wp1[i + 3];
        acc2 += v.x * wp2[i] + v.y * wp2[i + 1] + v.z * wp2[i + 2] + v.w * wp2[i + 3];
    }
#pragma unroll
    for (int d = 1; d < 8; d <<= 1) {
        acc1 += __shfl_xor(acc1, d, 64);
        acc2 += __shfl_xor(acc2, d, 64);
    }
    if (seg == 0) { s1[row] = acc1; s2[row] = acc2; }
}

// ---------------- K2: whT[o][r] = bf16( (h@W)[r][o] ) ----------------------
// 256 blocks (rt). h tile staged ONCE; ot loops inside (WT restaged per ot, L2-hot).
__global__ __launch_bounds__(256, 2)
void k_whT(const float* __restrict__ h, const unsigned short* __restrict__ WT,
           unsigned short* __restrict__ whT) {
    __shared__ __align__(16) unsigned char smem[65536]; // [0,32K): WT tile / LT epilogue, [32K,64K): h tile
    int tid = threadIdx.x, w = tid >> 6, l = tid & 63;
    int rt = blockIdx.x;
    unsigned short* h_lds = (unsigned short*)(smem + 32768);

    // stage h tile [64r][256i] f32->bf16, XOR-swizzled writes (read once from HBM)
    {
        int rl = tid >> 2, cs = tid & 3;
        const float* hp = h + ((size_t)(rt * 64 + rl)) * 256 + cs * 64;
        int swzh = (rl & 7) << 4;
        unsigned char* dst = (unsigned char*)(h_lds + rl * 256);
#pragma unroll
        for (int q = 0; q < 8; q++) {
            float4 v0 = *(const float4*)(hp + q * 8);
            float4 v1 = *(const float4*)(hp + q * 8 + 4);
            u16x8 pk;
            pk[0] = f2bf(v0.x); pk[1] = f2bf(v0.y); pk[2] = f2bf(v0.z); pk[3] = f2bf(v0.w);
            pk[4] = f2bf(v1.x); pk[5] = f2bf(v1.y); pk[6] = f2bf(v1.z); pk[7] = f2bf(v1.w);
            *(u16x8*)(dst + ((cs * 128 + q * 16) ^ swzh)) = pk;
        }
    }

    int l15 = l & 15, g = l >> 4;
    int oh = (w & 1) * 32, rh = (w >> 1) * 32;
    int swzr = (l15 & 7) << 4;
    f32x4 acc[4][2][2] = {};   // [ot][oi][rj]

#pragma unroll
    for (int ot = 0; ot < 4; ot++) {
        // stage WT tile [64o][256i] bf16 (source pre-swizzled)
        const unsigned char* WTb = (const unsigned char*)WT + (size_t)ot * 32768;
#pragma unroll
        for (int j = 0; j < 8; j++) {
            int chunk = w * 8 + j;
            int o = chunk * 2 + (l >> 5);
            int kb = (l & 31) * 16;
            gld_lds16(WTb + o * 512 + (kb ^ ((o & 7) << 4)), smem + chunk * 1024);
        }
        asm volatile("s_waitcnt vmcnt(0) lgkmcnt(0)" ::: "memory");
        __builtin_amdgcn_sched_barrier(0);
        __builtin_amdgcn_s_barrier();
#pragma unroll
        for (int kc = 0; kc < 8; kc++) {
            int kbyte = kc * 64 + 16 * g;
            bf16x8 A[2], Bv[2];
#pragma unroll
            for (int oi = 0; oi < 2; oi++)
                A[oi] = *(const bf16x8*)(smem + (oh + oi * 16 + l15) * 512 + (kbyte ^ swzr));
#pragma unroll
            for (int rj = 0; rj < 2; rj++)
                Bv[rj] = *(const bf16x8*)((unsigned char*)h_lds + (rh + rj * 16 + l15) * 512 + (kbyte ^ swzr));
#pragma unroll
            for (int oi = 0; oi < 2; oi++)
#pragma unroll
                for (int rj = 0; rj < 2; rj++)
                    acc[ot][oi][rj] = __builtin_amdgcn_mfma_f32_16x16x32_bf16(A[oi], Bv[rj], acc[ot][oi][rj], 0, 0, 0);
        }
        __builtin_amdgcn_s_barrier();   // before next ot overwrites WT tile
    }

    // epilogue: per ot, transpose via LDS (reuses WT region), coalesced stores
    unsigned short* LT = (unsigned short*)smem;   // [64o][72r]
#pragma unroll
    for (int ot = 0; ot < 4; ot++) {
#pragma unroll
        for (int oi = 0; oi < 2; oi++)
#pragma unroll
            for (int rj = 0; rj < 2; rj++)
#pragma unroll
                for (int jj = 0; jj < 4; jj++) {
                    int o = oh + oi * 16 + g * 4 + jj;
                    int r = rh + rj * 16 + l15;
                    LT[o * 72 + r] = f2bf(acc[ot][oi][rj][jj]);
                }
        __syncthreads();
        {
            int o = tid >> 2, seg = tid & 3;
            u16x8 v0 = *(const u16x8*)(LT + o * 72 + seg * 16);
            u16x8 v1 = *(const u16x8*)(LT + o * 72 + seg * 16 + 8);
            unsigned short* dst = whT + (size_t)(ot * 64 + o) * 16384 + rt * 64 + seg * 16;
            *(u16x8*)dst = v0;
            *(u16x8*)(dst + 8) = v1;
        }
        __syncthreads();
    }
}

// ---------------- K3: fused adj/exp/softmax/PV, double-buffered ------------
// 256 blocks (b = bid&7 XCD-pinned, mt = bid>>3), 512 threads, QBLK=64.
// adj read directly (134 MB streamed once), register-prefetched 1 tile ahead.
// Per-wave vmcnt/iter: 4 gld_lds + 2 adj = 6 -> s_waitcnt vmcnt(6) drains prev iter.
// LDS: buf0 [0,32K) buf1 [32K,64K) whT tiles [256o][64n]; P [65536,74752) 64x144B;
//      S2 [74752,82944); S1 [82944,83200); RS [83200,83456)
__global__ __launch_bounds__(512, 2)
void k_attn(const int* __restrict__ adj, const unsigned short* __restrict__ whT,
            const float* __restrict__ s1, const float* __restrict__ s2,
            float* __restrict__ out) {
    __shared__ __align__(16) unsigned char smem[83456];
    int tid = threadIdx.x, w = tid >> 6, l = tid & 63;
    int b = blockIdx.x & 7, mt = blockIdx.x >> 3;
    int m0 = mt * 64;
    unsigned short* P = (unsigned short*)(smem + 65536);
    float* S2 = (float*)(smem + 74752);
    float* S1 = (float*)(smem + 82944);
    float* RS = (float*)(smem + 83200);

    if (tid < 64) S1[tid] = s1[b * 2048 + m0 + tid];
    *(f32x4*)(S2 + tid * 4) = *(const f32x4*)(s2 + b * 2048 + tid * 4);

    const unsigned char* src0 = (const unsigned char*)whT + (size_t)(b * 2048) * 2;

    // prologue: stage tile 0 -> buf0 (4 gld_lds per wave), adj for nt=0
#pragma unroll
    for (int j = 0; j < 4; j++) {
        int chunk = w * 4 + j;
        int o = chunk * 8 + (l >> 3);
        int kb = (l & 7) * 16;
        gld_lds16(src0 + (size_t)o * 32768 + (kb ^ ((o & 7) << 4)), smem + chunk * 1024);
    }
    int tm = tid >> 3, ts = tid & 7;
    const int* adjRow = adj + ((size_t)(b * 2048 + m0 + tm)) * 2048 + ts * 8;
    int4 ca0 = *(const int4*)adjRow;
    int4 ca1 = *(const int4*)(adjRow + 4);

    asm volatile("s_waitcnt lgkmcnt(0)" ::: "memory");   // S1/S2 LDS writes
    __builtin_amdgcn_sched_barrier(0);
    __builtin_amdgcn_s_barrier();

    float s1v = S1[tm];
    f32x4 acc[2][4] = {};   // [oi][mj]
    f32x4 rs[2] = {};
    u16x8 onesu;
#pragma unroll
    for (int i = 0; i < 8; i++) onesu[i] = 0x3F80;
    bf16x8 ones = *(bf16x8*)&onesu;

    int l15 = l & 15, g = l >> 4;
    int swz = (l15 & 7) << 4;
    int cur = 0;
    int4 na0 = ca0, na1 = ca1;

    for (int nt = 0; nt < 32; nt++) {
        if (nt < 31) {
            // issue next tile's stage, then next adj (order matters for in-order vmcnt)
            unsigned bufoff = (unsigned)(cur ^ 1) * 32768u;
            int n0b = (nt + 1) * 128;
#pragma unroll
            for (int j = 0; j < 4; j++) {
                int chunk = w * 4 + j;
                int o = chunk * 8 + (l >> 3);
                int kb = (l & 7) * 16;
                gld_lds16(src0 + (size_t)o * 32768 + n0b + (kb ^ ((o & 7) << 4)),
                          smem + bufoff + chunk * 1024);
            }
            na0 = *(const int4*)(adjRow + (nt + 1) * 64);
            na1 = *(const int4*)(adjRow + (nt + 1) * 64 + 4);
            __builtin_amdgcn_sched_barrier(0);
        }
        // P[m][n'] from prefetched adj regs (bf16)
        {
            const float* s2p = S2 + nt * 64 + ts * 8;
            f32x4 sv0 = *(const f32x4*)s2p;
            f32x4 sv1 = *(const f32x4*)(s2p + 4);
            int av[8] = {ca0.x, ca0.y, ca0.z, ca0.w, ca1.x, ca1.y, ca1.z, ca1.w};
            u16x8 pk;
#pragma unroll
            for (int e = 0; e < 8; e++) {
                float x = s1v + (e < 4 ? sv0[e] : sv1[e - 4]);
                x = x > 0.f ? x : 0.2f * x;
                float p = av[e] > 0 ? __expf(x) : 0.f;
                pk[e] = f2bf(p);
            }
            *(u16x8*)((unsigned char*)P + tm * 144 + ts * 16) = pk;
        }
        // drain: all PREVIOUS-iter vmem (stage of buf[cur] + adj) done; keep 6 this-iter in flight
        if (nt < 31) asm volatile("s_waitcnt vmcnt(6) lgkmcnt(0)" ::: "memory");
        else         asm volatile("s_waitcnt vmcnt(0) lgkmcnt(0)" ::: "memory");
        __builtin_amdgcn_sched_barrier(0);
        __builtin_amdgcn_s_barrier();

        const unsigned char* bufb = smem + (unsigned)cur * 32768u;
        __builtin_amdgcn_s_setprio(1);
#pragma unroll
        for (int kc = 0; kc < 2; kc++) {
            int kbyte = kc * 64 + 16 * g;
            bf16x8 Bv[4];
#pragma unroll
            for (int mj = 0; mj < 4; mj++)
                Bv[mj] = *(const bf16x8*)((const unsigned char*)P + (mj * 16 + l15) * 144 + kbyte);
#pragma unroll
            for (int oi = 0; oi < 2; oi++) {
                bf16x8 Av = *(const bf16x8*)(bufb + (w * 32 + oi * 16 + l15) * 128 + (kbyte ^ swz));
#pragma unroll
                for (int mj = 0; mj < 4; mj++)
                    acc[oi][mj] = __builtin_amdgcn_mfma_f32_16x16x32_bf16(Av, Bv[mj], acc[oi][mj], 0, 0, 0);
            }
            if (w == 0) {
                rs[0] = __builtin_amdgcn_mfma_f32_16x16x32_bf16(ones, Bv[0], rs[0], 0, 0, 0);
                rs[1] = __builtin_amdgcn_mfma_f32_16x16x32_bf16(ones, Bv[1], rs[1], 0, 0, 0);
            }
            if (w == 4) {
                rs[0] = __builtin_amdgcn_mfma_f32_16x16x32_bf16(ones, Bv[2], rs[0], 0, 0, 0);
                rs[1] = __builtin_amdgcn_mfma_f32_16x16x32_bf16(ones, Bv[3], rs[1], 0, 0, 0);
            }
        }
        __builtin_amdgcn_s_setprio(0);
        __builtin_amdgcn_sched_barrier(0);
        __builtin_amdgcn_s_barrier();   // protect P before next-iter rewrite
        ca0 = na0; ca1 = na1;
        cur ^= 1;
    }

    if (w == 0 && l < 16) { RS[l] = rs[0][0]; RS[16 + l] = rs[1][0]; }
    if (w == 4 && l < 16) { RS[32 + l] = rs[0][0]; RS[48 + l] = rs[1][0]; }
    __syncthreads();
    float inv[4];
#pragma unroll
    for (int mj = 0; mj < 4; mj++) {
        float r_ = RS[mj * 16 + l15];
        inv[mj] = r_ > 0.f ? 1.0f / r_ : 0.f;
    }
    // epilogue: normalize + transpose via LDS (per-wave [64m][36o] f32), coalesced stores
    float* EP = (float*)(smem + w * 9216);
#pragma unroll
    for (int oi = 0; oi < 2; oi++)
#pragma unroll
        for (int mj = 0; mj < 4; mj++)
#pragma unroll
            for (int jj = 0; jj < 4; jj++)
                EP[(mj * 16 + l15) * 36 + oi * 16 + g * 4 + jj] = acc[oi][mj][jj] * inv[mj];
    __syncthreads();
    {
        int lm = l >> 2, os = l & 3;
#pragma unroll
        for (int rep = 0; rep < 4; rep++) {
            int m = rep * 16 + lm;
            int off = os * 8;
            f32x4 v0 = *(const f32x4*)(EP + m * 36 + off);
            f32x4 v1 = *(const f32x4*)(EP + m * 36 + off + 4);
            float* dst = out + ((size_t)b * 2048 + m0 + m) * 256 + w * 32 + off;
            *(f32x4*)dst = v0;
            *(f32x4*)(dst + 4) = v1;
        }
    }
}

extern "C" void kernel_launch(void* const* d_in, const int* in_sizes, int n_in,
                              void* d_out, int out_size, void* d_ws, size_t ws_size,
                              hipStream_t stream) {
    const float* h = (const float*)d_in[0];
    const int* adj = (const int*)d_in[1];
    const float* W = (const float*)d_in[2];
    const float* a = (const float*)d_in[3];
    float* out = (float*)d_out;

    unsigned char* ws = (unsigned char*)d_ws;
    unsigned short* whT = (unsigned short*)ws;                // 8,388,608
    unsigned short* WT  = (unsigned short*)(ws + 8388608);    //   131,072
    float* wa1 = (float*)(ws + 8519680);                      //     1,024
    float* wa2 = (float*)(ws + 8520704);                      //     1,024
    float* s1  = (float*)(ws + 8521728);                      //    65,536
    float* s2  = (float*)(ws + 8587264);                      //    65,536 (total ~8.65 MB)

    k_prep  <<<257, 256, 0, stream>>>(W, a, WT, wa1, wa2);
    k_scores<<<512, 256, 0, stream>>>(h, wa1, wa2, s1, s2);
    k_whT   <<<256, 256, 0, stream>>>(h, WT, whT);
    k_attn  <<<256, 512, 0, stream>>>(adj, whT, s1, s2, out);
}